// Round 7
// baseline (254.180 us; speedup 1.0000x reference)
//
#include <hip/hip_runtime.h>
#include <hip/hip_bf16.h>

#define BB 4
#define CC 64
#define OO 64
#define NN 32768
#define TT 4
#define KK 9
#define PADW 4
#define SIGMA 0.05f
#define EPS_BN 1e-5f

typedef __attribute__((ext_vector_type(8))) short bf16x8;
typedef __attribute__((ext_vector_type(4))) float f32x4;

__device__ __forceinline__ unsigned short f2bf(float f) {
  __hip_bfloat16 h = __float2bfloat16(f);
  return *reinterpret_cast<unsigned short*>(&h);
}
__device__ __forceinline__ float bf2f(unsigned short u) {
  unsigned int x = ((unsigned int)u) << 16;
  float f;
  __builtin_memcpy(&f, &x, 4);
  return f;
}
__device__ __forceinline__ unsigned int pkbf(float a, float b) {
  float2 t; t.x = a; t.y = b;
  __hip_bfloat162 h = __float22bfloat162_rn(t);
  unsigned int r;
  __builtin_memcpy(&r, &h, 4);
  return r;
}

// ---------------------------------------------------------------------------
// Prep 1: transpose input (B,C,N) f32 -> (B,N,C) bf16
// ---------------------------------------------------------------------------
__global__ __launch_bounds__(256) void transpose_kernel(
    const float* __restrict__ inp, unsigned short* __restrict__ xTb)
{
  const int n0 = blockIdx.x * 64;
  const int b  = blockIdx.y;
  const int tid = threadIdx.x;
  __shared__ float xt[64][65];
  {
    int nl = tid & 63, c4 = tid >> 6;
    #pragma unroll
    for (int i = 0; i < 16; ++i) {
      int c = c4 * 16 + i;
      xt[c][nl] = inp[((size_t)(b*CC + c))*NN + n0 + nl];
    }
  }
  __syncthreads();
  {
    int nl = tid >> 2, cq = tid & 3;
    unsigned int pk[8];
    #pragma unroll
    for (int i = 0; i < 8; ++i) {
      int c = cq*16 + i*2;
      pk[i] = pkbf(xt[c][nl], xt[c+1][nl]);
    }
    unsigned int* dst = (unsigned int*)(xTb + (((size_t)b*NN) + n0 + nl)*CC + cq*16);
    ((int4*)dst)[0] = make_int4((int)pk[0],(int)pk[1],(int)pk[2],(int)pk[3]);
    ((int4*)dst)[1] = make_int4((int)pk[4],(int)pk[5],(int)pk[6],(int)pk[7]);
  }
}

// ---------------------------------------------------------------------------
// Prep 2: conv weights (T,O,C,K) f32 -> fragment-order bf16
//   W4[(t*9+k)*4096 + ow*2048 + ot*1024 + frag*512 + l15*32 + q*8 + j]
// ---------------------------------------------------------------------------
__global__ __launch_bounds__(256) void wprep_kernel(
    const float* __restrict__ cw, unsigned short* __restrict__ W4)
{
  const int k = blockIdx.x;  // 0..8
  const int t = blockIdx.y;  // 0..3
  for (int u = threadIdx.x; u < OO*CC; u += 256) {
    int o = u >> 6, c = u & 63;
    int ow = o >> 5, ot = (o >> 4) & 1, l15 = o & 15;
    int frag = c >> 5, q = (c >> 3) & 3, j = c & 7;
    float wv = cw[(((size_t)(t*OO + o))*CC + c)*KK + k];
    W4[(size_t)(t*9+k)*4096 + ow*2048 + ot*1024 + frag*512 + l15*32 + q*8 + j]
        = f2bf(wv);
  }
}

// ---------------------------------------------------------------------------
// Conv: n-tile 128, waves 2x2 (32o x 64n each).  (unchanged from round 6)
// ---------------------------------------------------------------------------
__global__ __launch_bounds__(256, 4) void conv_kernel(
    const unsigned short* __restrict__ xTb,  // (B,N,C) bf16
    const float* __restrict__ mc,            // (B,3,N,T)
    const int*   __restrict__ ind,           // (B,N,T)
    const unsigned short* __restrict__ W4,   // fragment-order bf16
    unsigned short* __restrict__ Y,          // (T,B,N,O) bf16
    float* __restrict__ cpart2)              // (256 to, 2, 4096 slots)
{
  const int n0  = blockIdx.x * 128;
  const int b   = blockIdx.y;
  const int t   = blockIdx.z;
  const int tid = threadIdx.x;
  const int lane = tid & 63;
  const int w    = tid >> 6;
  const int l15  = lane & 15;
  const int q    = lane >> 4;
  const int ow   = w & 1;     // o half  (32 o's)
  const int nw   = w >> 1;    // n half  (64 n's)

  __shared__ short xg[136][72];      // gathered window rows (bf16 bits)
  __shared__ float wgl[128][10];     // window weights
  __shared__ float mcs[3][140];      // coords for this t, zero-padded

  // --- phase A: issue gather loads into registers
  int4 g[5];
  #pragma unroll
  for (int i = 0; i < 5; ++i) {
    int u = tid + 256*i;
    g[i] = make_int4(0,0,0,0);
    if (u < 1088) {
      int p = u >> 3, s = u & 7;
      int m = n0 + p - PADW;
      if (m >= 0 && m < NN) {
        int idx = ind[((size_t)b*NN + m)*TT + t];
        g[i] = *(const int4*)(xTb + ((size_t)b*NN + idx)*CC + s*8);
      }
    }
  }

  // --- phase B: coalesced mc staging (lane=point, 16B covers all 4 t)
  if (tid < 136) {
    int m = n0 + tid - PADW;
    #pragma unroll
    for (int d = 0; d < 3; ++d) {
      float4 v = make_float4(0.f, 0.f, 0.f, 0.f);
      if (m >= 0 && m < NN)
        v = *(const float4*)(mc + (((size_t)(b*3+d))*NN + m)*TT);
      mcs[d][tid] = (t==0) ? v.x : (t==1) ? v.y : (t==2) ? v.z : v.w;
    }
  }

  // --- commit gather to LDS
  #pragma unroll
  for (int i = 0; i < 5; ++i) {
    int u = tid + 256*i;
    if (u < 1088) {
      int p = u >> 3, s = u & 7;
      *(int4*)&xg[p][s*8] = g[i];
    }
  }
  __syncthreads();

  // --- phase C: window weights from LDS coords
  {
    int nl = tid >> 1;
    int k0 = (tid & 1) * 5;
    int kc = 5 - (tid & 1);
    float cx = mcs[0][nl+4], cy = mcs[1][nl+4], cz = mcs[2][nl+4];
    for (int i2 = 0; i2 < kc; ++i2) {
      int k = k0 + i2, mi = nl + k;
      float dx = mcs[0][mi]-cx, dy = mcs[1][mi]-cy, dz = mcs[2][mi]-cz;
      float s2 = dx*dx + dy*dy + dz*dz;
      float r = (s2 > 0.f) ? sqrtf(s2) : 0.f;
      wgl[nl][k] = fmaxf(1.f - r*(1.f/SIGMA), 0.f);
    }
  }
  __syncthreads();

  // --- MFMA loop
  const unsigned short* Wt = W4 + (size_t)t*9*4096 + ow*2048 + (l15*4 + q)*8;
  const f32x4 Z = {0.f, 0.f, 0.f, 0.f};
  f32x4 fin[2][4];
  #pragma unroll
  for (int ot = 0; ot < 2; ++ot)
    #pragma unroll
    for (int ns = 0; ns < 4; ++ns) fin[ot][ns] = Z;

  for (int k = 0; k < KK; ++k) {
    const unsigned short* Wk = Wt + (size_t)k*4096;
    bf16x8 af[2][2];
    #pragma unroll
    for (int ot = 0; ot < 2; ++ot) {
      af[ot][0] = *(const bf16x8*)(Wk + ot*1024);
      af[ot][1] = *(const bf16x8*)(Wk + ot*1024 + 512);
    }
    #pragma unroll
    for (int ns = 0; ns < 4; ++ns) {
      int nl = nw*64 + ns*16 + l15;
      int p  = nl + k;
      bf16x8 b0 = *(const bf16x8*)&xg[p][q*8];
      bf16x8 b1 = *(const bf16x8*)&xg[p][32 + q*8];
      float wgt = wgl[nl][k];
      #pragma unroll
      for (int ot = 0; ot < 2; ++ot) {
        f32x4 d = __builtin_amdgcn_mfma_f32_16x16x32_bf16(af[ot][0], b0, Z, 0, 0, 0);
        d = __builtin_amdgcn_mfma_f32_16x16x32_bf16(af[ot][1], b1, d, 0, 0, 0);
        fin[ot][ns] += wgt * d;
      }
    }
  }

  // --- register epilogue 1: direct Y stores, (T,B,N,O)
  #pragma unroll
  for (int ns = 0; ns < 4; ++ns) {
    int nl = nw*64 + ns*16 + l15;
    size_t row = (((size_t)t*BB + b)*NN + n0 + nl)*OO;
    #pragma unroll
    for (int ot = 0; ot < 2; ++ot) {
      uint2 pk2;
      pk2.x = pkbf(fin[ot][ns][0], fin[ot][ns][1]);
      pk2.y = pkbf(fin[ot][ns][2], fin[ot][ns][3]);
      *(uint2*)(Y + row + ow*32 + ot*16 + q*4) = pk2;
    }
  }

  // --- register epilogue 2: stats via shfl butterfly (width 16)
  float sv[16];
  #pragma unroll
  for (int ot = 0; ot < 2; ++ot)
    #pragma unroll
    for (int r = 0; r < 4; ++r) {
      float a = 0.f, qs = 0.f;
      #pragma unroll
      for (int ns = 0; ns < 4; ++ns) {
        float v = fin[ot][ns][r];
        a += v; qs += v*v;
      }
      sv[ot*4+r] = a; sv[8+ot*4+r] = qs;
    }
  #pragma unroll
  for (int msk = 1; msk < 16; msk <<= 1) {
    #pragma unroll
    for (int i = 0; i < 16; ++i) sv[i] += __shfl_xor(sv[i], msk, 16);
  }
  if (l15 == 0) {
    int slot4 = ((b*256 + (int)blockIdx.x) << 2) | w;   // [0,4096)
    #pragma unroll
    for (int ot = 0; ot < 2; ++ot)
      #pragma unroll
      for (int r = 0; r < 4; ++r) {
        int o = ow*32 + ot*16 + q*4 + r;
        cpart2[((size_t)((t*64 + o)*2 + 0))*4096 + slot4] = sv[ot*4+r];
        cpart2[((size_t)((t*64 + o)*2 + 1))*4096 + slot4] = sv[8+ot*4+r];
      }
  }
}

// ---------------------------------------------------------------------------
// Reduce conv partials -> per-(t,o) scale/shift.  Grid 256 = (t,o).
// ---------------------------------------------------------------------------
__global__ __launch_bounds__(256) void bnparam_kernel(
    const float* __restrict__ cpart2,  // (256,2,4096)
    const float* __restrict__ gam,
    const float* __restrict__ bet,
    float* __restrict__ ss)            // (T*O,2)
{
  const int to = blockIdx.x;
  const int tid = threadIdx.x;
  __shared__ float r1[256], r2[256];
  const float* p1 = cpart2 + (size_t)to*2*4096;
  const float* p2 = p1 + 4096;
  float s1 = 0.f, s2 = 0.f;
  for (int i = tid*4; i < 4096; i += 1024) {
    float4 a = *(const float4*)(p1 + i);
    float4 c = *(const float4*)(p2 + i);
    s1 += a.x + a.y + a.z + a.w;
    s2 += c.x + c.y + c.z + c.w;
  }
  r1[tid] = s1; r2[tid] = s2;
  __syncthreads();
  for (int st = 128; st > 0; st >>= 1) {
    if (tid < st) { r1[tid] += r1[tid+st]; r2[tid] += r2[tid+st]; }
    __syncthreads();
  }
  if (tid == 0) {
    const float inv = 1.f / (float)(BB * NN);
    float mean = r1[0] * inv;
    float var  = r2[0] * inv - mean * mean;
    float sc = gam[to] * rsqrtf(var + EPS_BN);
    ss[to*2 + 0] = sc;
    ss[to*2 + 1] = bet[to] - mean * sc;
  }
}

// ---------------------------------------------------------------------------
// bias2[o] = fb[o] + sum_c fw[o,c] * shift[c]   (shift = ss[c*2+1])
// ---------------------------------------------------------------------------
__global__ void bias2_kernel(
    const float* __restrict__ fw, const float* __restrict__ ss,
    const float* __restrict__ fb, float* __restrict__ bias2)
{
  int o = threadIdx.x;   // 64
  float s = fb[o];
  for (int c = 0; c < 256; ++c) s += fw[o*256 + c] * ss[c*2 + 1];
  bias2[o] = s;
}

// ---------------------------------------------------------------------------
// Fusion: BN folded into A (fw*scale) and bias2.  B loaded DIRECTLY from
// global Y into fragments (random 16B/lane).  No barriers in main loop.
// ---------------------------------------------------------------------------
__global__ __launch_bounds__(256) void fusion_kernel(
    const unsigned short* __restrict__ Y,   // (T,B,N,O) bf16
    const int*   __restrict__ rind,         // (B,N,T)
    const float* __restrict__ ss,           // (T*O,2)
    const float* __restrict__ fw,           // (O,256) f32
    const float* __restrict__ bias2,        // (O)
    float* __restrict__ out)                // (B,O,N) pre-BN
{
  const int n0  = blockIdx.x * 128;
  const int b   = blockIdx.y;
  const int tid = threadIdx.x;
  const int lane = tid & 63;
  const int w    = tid >> 6;
  const int l15  = lane & 15;
  const int q    = lane >> 4;
  const int ow   = w & 1;
  const int nw   = w >> 1;

  __shared__ int   rnl[TT][128];
  __shared__ float scl[256];
  __shared__ float b2l[64];

  if (tid < 128) {
    int4 r4 = *(const int4*)(rind + ((size_t)b*NN + n0 + tid)*TT);
    rnl[0][tid] = r4.x; rnl[1][tid] = r4.y;
    rnl[2][tid] = r4.z; rnl[3][tid] = r4.w;
  }
  scl[tid] = ss[tid*2];          // scale only
  if (tid < 64) b2l[tid] = bias2[tid];
  __syncthreads();               // the only barrier

  f32x4 fin[2][4];
  #pragma unroll
  for (int ot = 0; ot < 2; ++ot)
    #pragma unroll
    for (int ns = 0; ns < 4; ++ns) fin[ot][ns] = (f32x4){0.f,0.f,0.f,0.f};

  for (int r = 0; r < 4; ++r) {
    const unsigned short* Yb = Y + ((size_t)r*BB + b)*NN*OO;
    #pragma unroll
    for (int kk = 0; kk < 2; ++kk) {
      // A fragments: fw * conv-BN-scale, packed bf16
      bf16x8 af[2];
      #pragma unroll
      for (int ot = 0; ot < 2; ++ot) {
        const float* wp = fw + (size_t)(ow*32 + ot*16 + l15)*256 + r*64 + kk*32 + q*8;
        const float* sp = scl + r*64 + kk*32 + q*8;    // wave-uniform per q -> broadcast
        unsigned int pk[4];
        #pragma unroll
        for (int j = 0; j < 4; ++j)
          pk[j] = pkbf(wp[2*j]*sp[2*j], wp[2*j+1]*sp[2*j+1]);
        int4 tmp = make_int4((int)pk[0],(int)pk[1],(int)pk[2],(int)pk[3]);
        __builtin_memcpy(&af[ot], &tmp, 16);
      }
      // B fragments: raw bf16 Y rows, straight from global
      #pragma unroll
      for (int ns = 0; ns < 4; ++ns) {
        int nl = nw*64 + ns*16 + l15;
        int rn = rnl[r][nl];
        bf16x8 braw = *(const bf16x8*)(Yb + (size_t)rn*OO + kk*32 + q*8);
        #pragma unroll
        for (int ot = 0; ot < 2; ++ot)
          fin[ot][ns] = __builtin_amdgcn_mfma_f32_16x16x32_bf16(af[ot], braw, fin[ot][ns], 0, 0, 0);
      }
    }
  }

  // register epilogue: coalesced stores
  #pragma unroll
  for (int ot = 0; ot < 2; ++ot)
    #pragma unroll
    for (int rr = 0; rr < 4; ++rr) {
      int o = ow*32 + ot*16 + q*4 + rr;
      float bias = b2l[o];
      float* dst = out + ((size_t)(b*OO + o))*NN + n0 + nw*64;
      #pragma unroll
      for (int ns = 0; ns < 4; ++ns)
        dst[ns*16 + l15] = fin[ot][ns][rr] + bias;
    }
}

// ---------------------------------------------------------------------------
// Fusion-BN stats pass over the pre-BN output.  Grid (O, B).
// ---------------------------------------------------------------------------
__global__ __launch_bounds__(256) void fstat_kernel(
    const float* __restrict__ out, float* __restrict__ fpart)  // (B*O,2)
{
  const int o = blockIdx.x, b = blockIdx.y;
  const int tid = threadIdx.x;
  __shared__ float r1[256], r2[256];
  const float* src = out + ((size_t)(b*OO + o))*NN;
  float s1 = 0.f, s2 = 0.f;
  for (int i = tid*4; i < NN; i += 1024) {
    float4 v = *(const float4*)(src + i);
    s1 += v.x + v.y + v.z + v.w;
    s2 += v.x*v.x + v.y*v.y + v.z*v.z + v.w*v.w;
  }
  r1[tid] = s1; r2[tid] = s2;
  __syncthreads();
  for (int st = 128; st > 0; st >>= 1) {
    if (tid < st) { r1[tid] += r1[tid+st]; r2[tid] += r2[tid+st]; }
    __syncthreads();
  }
  if (tid == 0) {
    fpart[(b*OO + o)*2 + 0] = r1[0];
    fpart[(b*OO + o)*2 + 1] = r2[0];
  }
}

// ---------------------------------------------------------------------------
// Fold fusion partials -> per-o scale/shift.  1 block, 64 threads.
// ---------------------------------------------------------------------------
__global__ void freduce_kernel(
    const float* __restrict__ fpart,
    const float* __restrict__ fg,
    const float* __restrict__ fbeta,
    float* __restrict__ fss)
{
  int o = threadIdx.x;   // 64
  float s1 = 0.f, s2 = 0.f;
  #pragma unroll
  for (int b = 0; b < BB; ++b) {
    s1 += fpart[(b*OO + o)*2 + 0];
    s2 += fpart[(b*OO + o)*2 + 1];
  }
  const float inv = 1.f / (float)(BB * NN);
  float mean = s1 * inv;
  float var  = s2 * inv - mean * mean;
  float sc = fg[o] * rsqrtf(var + EPS_BN);
  fss[o*2 + 0] = sc;
  fss[o*2 + 1] = fbeta[o] - mean * sc;
}

// ---------------------------------------------------------------------------
// fusion BN + relu, in place (float4)
// ---------------------------------------------------------------------------
__global__ __launch_bounds__(256) void final_kernel(
    float* __restrict__ out, const float* __restrict__ fss)
{
  const size_t base = (size_t)blockIdx.x * 2048 + threadIdx.x * 4;
  #pragma unroll
  for (int s = 0; s < 2; ++s) {
    size_t e = base + (size_t)s * 1024;
    int o2 = (int)((e >> 15) & 63);
    float sc = fss[o2*2 + 0];
    float sh = fss[o2*2 + 1];
    float4 v = *(float4*)(out + e);
    v.x = fmaxf(v.x*sc + sh, 0.f);
    v.y = fmaxf(v.y*sc + sh, 0.f);
    v.z = fmaxf(v.z*sc + sh, 0.f);
    v.w = fmaxf(v.w*sc + sh, 0.f);
    *(float4*)(out + e) = v;
  }
}

// ---------------------------------------------------------------------------
extern "C" void kernel_launch(void* const* d_in, const int* in_sizes, int n_in,
                              void* d_out, int out_size, void* d_ws, size_t ws_size,
                              hipStream_t stream) {
  const float* inp  = (const float*)d_in[0];
  const float* mc   = (const float*)d_in[1];
  const int*   ind  = (const int*)  d_in[2];
  const int*   rind = (const int*)  d_in[3];
  const float* cw   = (const float*)d_in[4];
  const float* bg   = (const float*)d_in[5];
  const float* bb   = (const float*)d_in[6];
  const float* fw   = (const float*)d_in[7];
  const float* fb   = (const float*)d_in[8];
  const float* fg   = (const float*)d_in[9];
  const float* fbt  = (const float*)d_in[10];

  // ws: [0,2048) convss | [2048,2560) fss | [2560,4608) fpart |
  //     [4608,4864) bias2 | [8192,+64MiB) Y (T,B,N,O)
  char* ws = (char*)d_ws;
  float* convss = (float*)(ws + 0);
  float* fss    = (float*)(ws + 2048);
  float* fpart  = (float*)(ws + 2560);
  float* bias2  = (float*)(ws + 4608);
  unsigned short* Y = (unsigned short*)(ws + 8192);

  // scratch in d_out (all dead before fusion writes it):
  char* ob = (char*)d_out;
  unsigned short* xTb = (unsigned short*)ob;                 // 16,777,216 B
  unsigned short* W4  = (unsigned short*)(ob + 16777216);    //    294,912 B
  float*          cpart2 = (float*)(ob + 17072128);          //  8,388,608 B
  float* out = (float*)d_out;

  dim3 gt(NN/64, BB);
  transpose_kernel<<<gt, 256, 0, stream>>>(inp, xTb);

  dim3 gw(KK, TT);
  wprep_kernel<<<gw, 256, 0, stream>>>(cw, W4);

  dim3 gc(NN/128, BB, TT);
  conv_kernel<<<gc, 256, 0, stream>>>(xTb, mc, ind, W4, Y, cpart2);

  bnparam_kernel<<<256, 256, 0, stream>>>(cpart2, bg, bb, convss);

  bias2_kernel<<<1, 64, 0, stream>>>(fw, convss, fb, bias2);

  dim3 gf(NN/128, BB);
  fusion_kernel<<<gf, 256, 0, stream>>>(Y, rind, convss, fw, bias2, out);

  dim3 gs(OO, BB);
  fstat_kernel<<<gs, 256, 0, stream>>>(out, fpart);

  freduce_kernel<<<1, 64, 0, stream>>>(fpart, fg, fbt, fss);

  final_kernel<<<(BB*OO*NN)/2048, 256, 0, stream>>>(out, fss);
}

// Round 8
// 242.813 us; speedup vs baseline: 1.0468x; 1.0468x over previous
//
#include <hip/hip_runtime.h>
#include <hip/hip_bf16.h>

#define BB 4
#define CC 64
#define OO 64
#define NN 32768
#define TT 4
#define KK 9
#define PADW 4
#define SIGMA 0.05f
#define EPS_BN 1e-5f

typedef __attribute__((ext_vector_type(8))) short bf16x8;
typedef __attribute__((ext_vector_type(4))) float f32x4;

__device__ __forceinline__ unsigned short f2bf(float f) {
  __hip_bfloat16 h = __float2bfloat16(f);
  return *reinterpret_cast<unsigned short*>(&h);
}
__device__ __forceinline__ unsigned int pkbf(float a, float b) {
  float2 t; t.x = a; t.y = b;
  __hip_bfloat162 h = __float22bfloat162_rn(t);
  unsigned int r;
  __builtin_memcpy(&r, &h, 4);
  return r;
}

// ---------------------------------------------------------------------------
// Prep 1: transpose input (B,C,N) f32 -> (B,N,C) bf16
// ---------------------------------------------------------------------------
__global__ __launch_bounds__(256) void transpose_kernel(
    const float* __restrict__ inp, unsigned short* __restrict__ xTb)
{
  const int n0 = blockIdx.x * 64;
  const int b  = blockIdx.y;
  const int tid = threadIdx.x;
  __shared__ float xt[64][65];
  {
    int nl = tid & 63, c4 = tid >> 6;
    #pragma unroll
    for (int i = 0; i < 16; ++i) {
      int c = c4 * 16 + i;
      xt[c][nl] = inp[((size_t)(b*CC + c))*NN + n0 + nl];
    }
  }
  __syncthreads();
  {
    int nl = tid >> 2, cq = tid & 3;
    unsigned int pk[8];
    #pragma unroll
    for (int i = 0; i < 8; ++i) {
      int c = cq*16 + i*2;
      pk[i] = pkbf(xt[c][nl], xt[c+1][nl]);
    }
    unsigned int* dst = (unsigned int*)(xTb + (((size_t)b*NN) + n0 + nl)*CC + cq*16);
    ((int4*)dst)[0] = make_int4((int)pk[0],(int)pk[1],(int)pk[2],(int)pk[3]);
    ((int4*)dst)[1] = make_int4((int)pk[4],(int)pk[5],(int)pk[6],(int)pk[7]);
  }
}

// ---------------------------------------------------------------------------
// Prep 2: conv weights (T,O,C,K) f32 -> fragment-order bf16
// ---------------------------------------------------------------------------
__global__ __launch_bounds__(256) void wprep_kernel(
    const float* __restrict__ cw, unsigned short* __restrict__ W4)
{
  const int k = blockIdx.x;  // 0..8
  const int t = blockIdx.y;  // 0..3
  for (int u = threadIdx.x; u < OO*CC; u += 256) {
    int o = u >> 6, c = u & 63;
    int ow = o >> 5, ot = (o >> 4) & 1, l15 = o & 15;
    int frag = c >> 5, q = (c >> 3) & 3, j = c & 7;
    float wv = cw[(((size_t)(t*OO + o))*CC + c)*KK + k];
    W4[(size_t)(t*9+k)*4096 + ow*2048 + ot*1024 + frag*512 + l15*32 + q*8 + j]
        = f2bf(wv);
  }
}

// ---------------------------------------------------------------------------
// Conv: n-tile 128, waves 2x2 (32o x 64n each).  (unchanged from round 6)
// ---------------------------------------------------------------------------
__global__ __launch_bounds__(256, 4) void conv_kernel(
    const unsigned short* __restrict__ xTb,  // (B,N,C) bf16
    const float* __restrict__ mc,            // (B,3,N,T)
    const int*   __restrict__ ind,           // (B,N,T)
    const unsigned short* __restrict__ W4,   // fragment-order bf16
    unsigned short* __restrict__ Y,          // (T,B,N,O) bf16
    float* __restrict__ cpart2)              // (256 to, 2, 4096 slots)
{
  const int n0  = blockIdx.x * 128;
  const int b   = blockIdx.y;
  const int t   = blockIdx.z;
  const int tid = threadIdx.x;
  const int lane = tid & 63;
  const int w    = tid >> 6;
  const int l15  = lane & 15;
  const int q    = lane >> 4;
  const int ow   = w & 1;     // o half  (32 o's)
  const int nw   = w >> 1;    // n half  (64 n's)

  __shared__ short xg[136][72];      // gathered window rows (bf16 bits)
  __shared__ float wgl[128][10];     // window weights
  __shared__ float mcs[3][140];      // coords for this t, zero-padded

  // --- phase A: issue gather loads into registers
  int4 g[5];
  #pragma unroll
  for (int i = 0; i < 5; ++i) {
    int u = tid + 256*i;
    g[i] = make_int4(0,0,0,0);
    if (u < 1088) {
      int p = u >> 3, s = u & 7;
      int m = n0 + p - PADW;
      if (m >= 0 && m < NN) {
        int idx = ind[((size_t)b*NN + m)*TT + t];
        g[i] = *(const int4*)(xTb + ((size_t)b*NN + idx)*CC + s*8);
      }
    }
  }

  // --- phase B: coalesced mc staging (lane=point, 16B covers all 4 t)
  if (tid < 136) {
    int m = n0 + tid - PADW;
    #pragma unroll
    for (int d = 0; d < 3; ++d) {
      float4 v = make_float4(0.f, 0.f, 0.f, 0.f);
      if (m >= 0 && m < NN)
        v = *(const float4*)(mc + (((size_t)(b*3+d))*NN + m)*TT);
      mcs[d][tid] = (t==0) ? v.x : (t==1) ? v.y : (t==2) ? v.z : v.w;
    }
  }

  // --- commit gather to LDS
  #pragma unroll
  for (int i = 0; i < 5; ++i) {
    int u = tid + 256*i;
    if (u < 1088) {
      int p = u >> 3, s = u & 7;
      *(int4*)&xg[p][s*8] = g[i];
    }
  }
  __syncthreads();

  // --- phase C: window weights from LDS coords
  {
    int nl = tid >> 1;
    int k0 = (tid & 1) * 5;
    int kc = 5 - (tid & 1);
    float cx = mcs[0][nl+4], cy = mcs[1][nl+4], cz = mcs[2][nl+4];
    for (int i2 = 0; i2 < kc; ++i2) {
      int k = k0 + i2, mi = nl + k;
      float dx = mcs[0][mi]-cx, dy = mcs[1][mi]-cy, dz = mcs[2][mi]-cz;
      float s2 = dx*dx + dy*dy + dz*dz;
      float r = (s2 > 0.f) ? sqrtf(s2) : 0.f;
      wgl[nl][k] = fmaxf(1.f - r*(1.f/SIGMA), 0.f);
    }
  }
  __syncthreads();

  // --- MFMA loop
  const unsigned short* Wt = W4 + (size_t)t*9*4096 + ow*2048 + (l15*4 + q)*8;
  const f32x4 Z = {0.f, 0.f, 0.f, 0.f};
  f32x4 fin[2][4];
  #pragma unroll
  for (int ot = 0; ot < 2; ++ot)
    #pragma unroll
    for (int ns = 0; ns < 4; ++ns) fin[ot][ns] = Z;

  for (int k = 0; k < KK; ++k) {
    const unsigned short* Wk = Wt + (size_t)k*4096;
    bf16x8 af[2][2];
    #pragma unroll
    for (int ot = 0; ot < 2; ++ot) {
      af[ot][0] = *(const bf16x8*)(Wk + ot*1024);
      af[ot][1] = *(const bf16x8*)(Wk + ot*1024 + 512);
    }
    #pragma unroll
    for (int ns = 0; ns < 4; ++ns) {
      int nl = nw*64 + ns*16 + l15;
      int p  = nl + k;
      bf16x8 b0 = *(const bf16x8*)&xg[p][q*8];
      bf16x8 b1 = *(const bf16x8*)&xg[p][32 + q*8];
      float wgt = wgl[nl][k];
      #pragma unroll
      for (int ot = 0; ot < 2; ++ot) {
        f32x4 d = __builtin_amdgcn_mfma_f32_16x16x32_bf16(af[ot][0], b0, Z, 0, 0, 0);
        d = __builtin_amdgcn_mfma_f32_16x16x32_bf16(af[ot][1], b1, d, 0, 0, 0);
        fin[ot][ns] += wgt * d;
      }
    }
  }

  // --- register epilogue 1: direct Y stores, (T,B,N,O)
  #pragma unroll
  for (int ns = 0; ns < 4; ++ns) {
    int nl = nw*64 + ns*16 + l15;
    size_t row = (((size_t)t*BB + b)*NN + n0 + nl)*OO;
    #pragma unroll
    for (int ot = 0; ot < 2; ++ot) {
      uint2 pk2;
      pk2.x = pkbf(fin[ot][ns][0], fin[ot][ns][1]);
      pk2.y = pkbf(fin[ot][ns][2], fin[ot][ns][3]);
      *(uint2*)(Y + row + ow*32 + ot*16 + q*4) = pk2;
    }
  }

  // --- register epilogue 2: stats via shfl butterfly (width 16)
  float sv[16];
  #pragma unroll
  for (int ot = 0; ot < 2; ++ot)
    #pragma unroll
    for (int r = 0; r < 4; ++r) {
      float a = 0.f, qs = 0.f;
      #pragma unroll
      for (int ns = 0; ns < 4; ++ns) {
        float v = fin[ot][ns][r];
        a += v; qs += v*v;
      }
      sv[ot*4+r] = a; sv[8+ot*4+r] = qs;
    }
  #pragma unroll
  for (int msk = 1; msk < 16; msk <<= 1) {
    #pragma unroll
    for (int i = 0; i < 16; ++i) sv[i] += __shfl_xor(sv[i], msk, 16);
  }
  if (l15 == 0) {
    int slot4 = ((b*256 + (int)blockIdx.x) << 2) | w;   // [0,4096)
    #pragma unroll
    for (int ot = 0; ot < 2; ++ot)
      #pragma unroll
      for (int r = 0; r < 4; ++r) {
        int o = ow*32 + ot*16 + q*4 + r;
        cpart2[((size_t)((t*64 + o)*2 + 0))*4096 + slot4] = sv[ot*4+r];
        cpart2[((size_t)((t*64 + o)*2 + 1))*4096 + slot4] = sv[8+ot*4+r];
      }
  }
}

// ---------------------------------------------------------------------------
// Reduce conv partials -> per-(t,o) scale/shift.  Grid 256 = (t,o).
// ---------------------------------------------------------------------------
__global__ __launch_bounds__(256) void bnparam_kernel(
    const float* __restrict__ cpart2,  // (256,2,4096)
    const float* __restrict__ gam,
    const float* __restrict__ bet,
    float* __restrict__ ss)            // (T*O,2)
{
  const int to = blockIdx.x;
  const int tid = threadIdx.x;
  __shared__ float r1[256], r2[256];
  const float* p1 = cpart2 + (size_t)to*2*4096;
  const float* p2 = p1 + 4096;
  float s1 = 0.f, s2 = 0.f;
  for (int i = tid*4; i < 4096; i += 1024) {
    float4 a = *(const float4*)(p1 + i);
    float4 c = *(const float4*)(p2 + i);
    s1 += a.x + a.y + a.z + a.w;
    s2 += c.x + c.y + c.z + c.w;
  }
  r1[tid] = s1; r2[tid] = s2;
  __syncthreads();
  for (int st = 128; st > 0; st >>= 1) {
    if (tid < st) { r1[tid] += r1[tid+st]; r2[tid] += r2[tid+st]; }
    __syncthreads();
  }
  if (tid == 0) {
    const float inv = 1.f / (float)(BB * NN);
    float mean = r1[0] * inv;
    float var  = r2[0] * inv - mean * mean;
    float sc = gam[to] * rsqrtf(var + EPS_BN);
    ss[to*2 + 0] = sc;
    ss[to*2 + 1] = bet[to] - mean * sc;
  }
}

// ---------------------------------------------------------------------------
// Fusion: cooperative LDS staging of RAW Y rows (each row read once),
// BN folded into A-frags (fw*scale) and bias2 (computed in prologue).
// ---------------------------------------------------------------------------
__global__ __launch_bounds__(256) void fusion_kernel(
    const unsigned short* __restrict__ Y,   // (T,B,N,O) bf16
    const int*   __restrict__ rind,         // (B,N,T)
    const float* __restrict__ ss,           // (T*O,2)
    const float* __restrict__ fw,           // (O,256) f32
    const float* __restrict__ fb,           // (O)
    float* __restrict__ out)                // (B,O,N) pre-BN
{
  const int n0  = blockIdx.x * 128;
  const int b   = blockIdx.y;
  const int tid = threadIdx.x;
  const int lane = tid & 63;
  const int w    = tid >> 6;
  const int l15  = lane & 15;
  const int q    = lane >> 4;
  const int ow   = w & 1;
  const int nw   = w >> 1;

  __shared__ short zg[128][72];     // one K-quarter of raw Y rows (18,432 B)
  __shared__ int   rnl[TT][128];
  __shared__ float scl[256];
  __shared__ float b2l[64];
  __shared__ float bred[4][64];

  if (tid < 128) {
    int4 r4 = *(const int4*)(rind + ((size_t)b*NN + n0 + tid)*TT);
    rnl[0][tid] = r4.x; rnl[1][tid] = r4.y;
    rnl[2][tid] = r4.z; rnl[3][tid] = r4.w;
  }
  scl[tid] = ss[tid*2];
  {  // bias2 partial: thread (g = tid>>6) covers c in [g*64, g*64+64)
    int o = tid & 63, g = tid >> 6;
    const float* wp = fw + (size_t)o*256 + g*64;
    float s = 0.f;
    for (int j = 0; j < 64; ++j) s += wp[j] * ss[(g*64 + j)*2 + 1];
    bred[g][o] = s;
  }
  __syncthreads();
  if (tid < 64)
    b2l[tid] = fb[tid] + bred[0][tid] + bred[1][tid] + bred[2][tid] + bred[3][tid];
  // b2l is read after at least one more barrier (stage barrier below) -> safe

  f32x4 fin[2][4];
  #pragma unroll
  for (int ot = 0; ot < 2; ++ot)
    #pragma unroll
    for (int ns = 0; ns < 4; ++ns) fin[ot][ns] = (f32x4){0.f,0.f,0.f,0.f};

  for (int r = 0; r < 4; ++r) {     // K-quarter == t index
    if (r) __syncthreads();         // previous compute done reading zg
    const unsigned short* Yb = Y + ((size_t)r*BB + b)*NN*OO;
    #pragma unroll
    for (int i = 0; i < 4; ++i) {   // raw copy: 128 rows x 8 chunks of 16B
      int u = tid + 256*i;
      int n = u >> 3, s = u & 7;
      int rn = rnl[r][n];
      *(int4*)&zg[n][s*8] = *(const int4*)(Yb + (size_t)rn*OO + s*8);
    }
    __syncthreads();

    #pragma unroll
    for (int kk = 0; kk < 2; ++kk) {
      bf16x8 af[2];
      #pragma unroll
      for (int ot = 0; ot < 2; ++ot) {
        const float* wp = fw + (size_t)(ow*32 + ot*16 + l15)*256 + r*64 + kk*32 + q*8;
        const float* sp = scl + r*64 + kk*32 + q*8;   // wave-uniform -> broadcast
        unsigned int pk[4];
        #pragma unroll
        for (int j = 0; j < 4; ++j)
          pk[j] = pkbf(wp[2*j]*sp[2*j], wp[2*j+1]*sp[2*j+1]);
        int4 tmp = make_int4((int)pk[0],(int)pk[1],(int)pk[2],(int)pk[3]);
        __builtin_memcpy(&af[ot], &tmp, 16);
      }
      #pragma unroll
      for (int ns = 0; ns < 4; ++ns) {
        int nl = nw*64 + ns*16 + l15;
        bf16x8 bfr = *(const bf16x8*)&zg[nl][kk*32 + q*8];
        #pragma unroll
        for (int ot = 0; ot < 2; ++ot)
          fin[ot][ns] = __builtin_amdgcn_mfma_f32_16x16x32_bf16(af[ot], bfr, fin[ot][ns], 0, 0, 0);
      }
    }
  }

  // register epilogue: coalesced stores
  #pragma unroll
  for (int ot = 0; ot < 2; ++ot)
    #pragma unroll
    for (int rr = 0; rr < 4; ++rr) {
      int o = ow*32 + ot*16 + q*4 + rr;
      float bias = b2l[o];
      float* dst = out + ((size_t)(b*OO + o))*NN + n0 + nw*64;
      #pragma unroll
      for (int ns = 0; ns < 4; ++ns)
        dst[ns*16 + l15] = fin[ot][ns][rr] + bias;
    }
}

// ---------------------------------------------------------------------------
// Fusion-BN stats pass over the pre-BN output.  Grid (O, B).
// ---------------------------------------------------------------------------
__global__ __launch_bounds__(256) void fstat_kernel(
    const float* __restrict__ out, float* __restrict__ fpart)  // (B*O,2)
{
  const int o = blockIdx.x, b = blockIdx.y;
  const int tid = threadIdx.x;
  __shared__ float r1[256], r2[256];
  const float* src = out + ((size_t)(b*OO + o))*NN;
  float s1 = 0.f, s2 = 0.f;
  for (int i = tid*4; i < NN; i += 1024) {
    float4 v = *(const float4*)(src + i);
    s1 += v.x + v.y + v.z + v.w;
    s2 += v.x*v.x + v.y*v.y + v.z*v.z + v.w*v.w;
  }
  r1[tid] = s1; r2[tid] = s2;
  __syncthreads();
  for (int st = 128; st > 0; st >>= 1) {
    if (tid < st) { r1[tid] += r1[tid+st]; r2[tid] += r2[tid+st]; }
    __syncthreads();
  }
  if (tid == 0) {
    fpart[(b*OO + o)*2 + 0] = r1[0];
    fpart[(b*OO + o)*2 + 1] = r2[0];
  }
}

// ---------------------------------------------------------------------------
// final: inline freduce (redundant per block, tiny) + BN + relu, in place
// ---------------------------------------------------------------------------
__global__ __launch_bounds__(256) void final_kernel(
    float* __restrict__ out, const float* __restrict__ fpart,
    const float* __restrict__ fg, const float* __restrict__ fbeta)
{
  __shared__ float fssl[128];
  const int tid = threadIdx.x;
  if (tid < 64) {
    float s1 = 0.f, s2 = 0.f;
    #pragma unroll
    for (int b = 0; b < BB; ++b) {
      s1 += fpart[(b*OO + tid)*2 + 0];
      s2 += fpart[(b*OO + tid)*2 + 1];
    }
    const float inv = 1.f / (float)(BB * NN);
    float mean = s1 * inv;
    float var  = s2 * inv - mean * mean;
    float sc = fg[tid] * rsqrtf(var + EPS_BN);
    fssl[tid*2 + 0] = sc;
    fssl[tid*2 + 1] = fbeta[tid] - mean * sc;
  }
  __syncthreads();
  const size_t base = (size_t)blockIdx.x * 2048 + tid * 4;
  #pragma unroll
  for (int s = 0; s < 2; ++s) {
    size_t e = base + (size_t)s * 1024;
    int o2 = (int)((e >> 15) & 63);
    float sc = fssl[o2*2 + 0];
    float sh = fssl[o2*2 + 1];
    float4 v = *(float4*)(out + e);
    v.x = fmaxf(v.x*sc + sh, 0.f);
    v.y = fmaxf(v.y*sc + sh, 0.f);
    v.z = fmaxf(v.z*sc + sh, 0.f);
    v.w = fmaxf(v.w*sc + sh, 0.f);
    *(float4*)(out + e) = v;
  }
}

// ---------------------------------------------------------------------------
extern "C" void kernel_launch(void* const* d_in, const int* in_sizes, int n_in,
                              void* d_out, int out_size, void* d_ws, size_t ws_size,
                              hipStream_t stream) {
  const float* inp  = (const float*)d_in[0];
  const float* mc   = (const float*)d_in[1];
  const int*   ind  = (const int*)  d_in[2];
  const int*   rind = (const int*)  d_in[3];
  const float* cw   = (const float*)d_in[4];
  const float* bg   = (const float*)d_in[5];
  const float* bb   = (const float*)d_in[6];
  const float* fw   = (const float*)d_in[7];
  const float* fb   = (const float*)d_in[8];
  const float* fg   = (const float*)d_in[9];
  const float* fbt  = (const float*)d_in[10];

  // ws: [0,2048) convss | [2560,4608) fpart | [8192,+64MiB) Y (T,B,N,O)
  char* ws = (char*)d_ws;
  float* convss = (float*)(ws + 0);
  float* fpart  = (float*)(ws + 2560);
  unsigned short* Y = (unsigned short*)(ws + 8192);

  // scratch in d_out (all dead before fusion writes it):
  char* ob = (char*)d_out;
  unsigned short* xTb = (unsigned short*)ob;                 // 16,777,216 B
  unsigned short* W4  = (unsigned short*)(ob + 16777216);    //    294,912 B
  float*          cpart2 = (float*)(ob + 17072128);          //  8,388,608 B
  float* out = (float*)d_out;

  dim3 gt(NN/64, BB);
  transpose_kernel<<<gt, 256, 0, stream>>>(inp, xTb);

  dim3 gw(KK, TT);
  wprep_kernel<<<gw, 256, 0, stream>>>(cw, W4);

  dim3 gc(NN/128, BB, TT);
  conv_kernel<<<gc, 256, 0, stream>>>(xTb, mc, ind, W4, Y, cpart2);

  bnparam_kernel<<<256, 256, 0, stream>>>(cpart2, bg, bb, convss);

  dim3 gf(NN/128, BB);
  fusion_kernel<<<gf, 256, 0, stream>>>(Y, rind, convss, fw, fb, out);

  dim3 gs(OO, BB);
  fstat_kernel<<<gs, 256, 0, stream>>>(out, fpart);

  final_kernel<<<(BB*OO*NN)/2048, 256, 0, stream>>>(out, fpart, fg, fbt);
}